// Round 9
// baseline (49.574 us; speedup 1.0000x reference)
//
#include <hip/hip_runtime.h>

#define BSES 64
#define EDIM 128
#define HDIM 128
#define KSCALE 2.8853900817779268f  // 2*log2(e): exp(2x) = exp2(KSCALE*x)

__device__ __forceinline__ float fexp2(float x) {
#if __has_builtin(__builtin_amdgcn_exp2f)
  return __builtin_amdgcn_exp2f(x);
#else
  return exp2f(x);
#endif
}
__device__ __forceinline__ float frcp(float x) {
#if __has_builtin(__builtin_amdgcn_rcpf)
  return __builtin_amdgcn_rcpf(x);
#else
  return 1.0f / x;
#endif
}

// 4-way batched reciprocal sum: w0/x0 + w1/x1 + w2/x2 + w3/x3,
// x_j = fma(s_j, v_j, 1). 13 VALU + 1 rcp per 4 elements. (Proven R3+.)
__device__ __forceinline__ float g4(float s0, float s1, float s2, float s3,
                                    float w0, float w1, float w2, float w3,
                                    float4 v, float acc) {
  float x0 = fmaf(s0, v.x, 1.f);
  float x1 = fmaf(s1, v.y, 1.f);
  float x2 = fmaf(s2, v.z, 1.f);
  float x3 = fmaf(s3, v.w, 1.f);
  float p01 = x0 * x1, p23 = x2 * x3;
  float n01 = fmaf(w1, x0, w0 * x1);
  float n23 = fmaf(w3, x2, w2 * x3);
  float num = fmaf(n23, p01, n01 * p23);
  return fmaf(num, frcp(p01 * p23), acc);
}

// Fused projections (R3-proven shape; UNCHANGED from R8). Blocks [0,nbTP):
// tp-projection, 32 targets each, output TRANSPOSED-PACKED etpT4[hq][n][4].
// Blocks [nbTP,..): esp[b][h] natural layout; plus C = sum(W3)+b3.
__global__ __launch_bounds__(256) void taa_k1(
    const float* __restrict__ sess, const float* __restrict__ W1,
    const float* __restrict__ b1, const float* __restrict__ emb,
    const float* __restrict__ W2, const float* __restrict__ b2,
    const float* __restrict__ W3, const float* __restrict__ b3,
    float* __restrict__ etpT4, float* __restrict__ esp,
    float* __restrict__ C_out, int N, int npad, int nbTP) {
  if ((int)blockIdx.x < nbTP) {
    __shared__ float sm[32][132];  // emb tile, padded stride
    const int nb = blockIdx.x * 32;
    for (int k = threadIdx.x; k < 32 * 32; k += 256) {
      int r = k >> 5, c4 = k & 31;
      float4 v = make_float4(0.f, 0.f, 0.f, 0.f);
      if (nb + r < N) v = ((const float4*)(emb + (size_t)(nb + r) * EDIM))[c4];
      *(float4*)&sm[r][c4 * 4] = v;
    }
    __syncthreads();
    const int hq = threadIdx.x & 31;  // h-quad index = output plane
    const int h4 = hq * 4;
    const int rg = threadIdx.x >> 5;  // 8 groups of 4 rows
    float acc[4][4];
#pragma unroll
    for (int j = 0; j < 4; ++j)
#pragma unroll
      for (int q = 0; q < 4; ++q) acc[j][q] = 0.f;
    for (int e = 0; e < EDIM; e += 4) {
      float4 w[4];
#pragma unroll
      for (int q = 0; q < 4; ++q)
        w[q] = *(const float4*)(W2 + (size_t)(e + q) * HDIM + h4);
#pragma unroll
      for (int j = 0; j < 4; ++j) {
        float4 em = *(const float4*)&sm[rg * 4 + j][e];
        acc[j][0] = fmaf(em.x, w[0].x, acc[j][0]);
        acc[j][1] = fmaf(em.x, w[0].y, acc[j][1]);
        acc[j][2] = fmaf(em.x, w[0].z, acc[j][2]);
        acc[j][3] = fmaf(em.x, w[0].w, acc[j][3]);
        acc[j][0] = fmaf(em.y, w[1].x, acc[j][0]);
        acc[j][1] = fmaf(em.y, w[1].y, acc[j][1]);
        acc[j][2] = fmaf(em.y, w[1].z, acc[j][2]);
        acc[j][3] = fmaf(em.y, w[1].w, acc[j][3]);
        acc[j][0] = fmaf(em.z, w[2].x, acc[j][0]);
        acc[j][1] = fmaf(em.z, w[2].y, acc[j][1]);
        acc[j][2] = fmaf(em.z, w[2].z, acc[j][2]);
        acc[j][3] = fmaf(em.z, w[2].w, acc[j][3]);
        acc[j][0] = fmaf(em.w, w[3].x, acc[j][0]);
        acc[j][1] = fmaf(em.w, w[3].y, acc[j][1]);
        acc[j][2] = fmaf(em.w, w[3].z, acc[j][2]);
        acc[j][3] = fmaf(em.w, w[3].w, acc[j][3]);
      }
    }
    float4 bb2 = *(const float4*)(b2 + h4);
#pragma unroll
    for (int j = 0; j < 4; ++j) {
      int n = nb + rg * 4 + j;
      if (n < N) {
        float4 o;
        o.x = fexp2((acc[j][0] + bb2.x) * KSCALE);
        o.y = fexp2((acc[j][1] + bb2.y) * KSCALE);
        o.z = fexp2((acc[j][2] + bb2.z) * KSCALE);
        o.w = fexp2((acc[j][3] + bb2.w) * KSCALE);
        *(float4*)(etpT4 + ((size_t)hq * npad + n) * 4) = o;
      }
    }
  } else {
    int t = ((int)blockIdx.x - nbTP) * 256 + threadIdx.x;
    if (t < BSES * HDIM) {
      int b = t >> 7, h = t & 127;
      const float* srow = sess + b * EDIM;
      float acc = 0.f;
#pragma unroll 4
      for (int e = 0; e < EDIM; ++e)
        acc = fmaf(srow[e], W1[e * HDIM + h], acc);
      esp[t] = fexp2((acc + b1[h]) * KSCALE);  // natural [b][h] layout
    }
    if (t == 0) {
      float s = b3[0];
      for (int i = 0; i < HDIM; ++i) s += W3[i];
      *C_out = s;
    }
  }
}

// Scoring: lane = target (64/wave). Session-group = 2 (HALVED from R8's 4):
// wave W -> tile = W/32, sessions (W%32)*2..+1. 10016 waves total (122% of
// the 8192 wave slots) for load balance + 8 waves/SIMD latency hiding.
// Per h-quarter: 8 coalesced dwordx4 et loads; esp/w3 wave-uniform s_loads.
__global__ __launch_bounds__(256) void taa_k2(
    const float* __restrict__ etpT4, const float* __restrict__ esp,
    const float* __restrict__ w3, const float* __restrict__ Cptr,
    float* __restrict__ out, int N, int npad) {
  const int lane = threadIdx.x & 63;
  const int wv = __builtin_amdgcn_readfirstlane((int)(threadIdx.x >> 6));
  const int W = blockIdx.x * 4 + wv;
  const int tile = W >> 5;
  const int s0 = (W & 31) * 2;
  const int n = tile * 64 + lane;  // < npad (loads safe; store guarded)
  float acc[2] = {0.f, 0.f};
#pragma unroll 1
  for (int q = 0; q < 4; ++q) {
    float4 ev[8];
#pragma unroll
    for (int k = 0; k < 8; ++k)
      ev[k] = *(const float4*)(etpT4 + (((q << 3) + k) * (size_t)npad + n) * 4);
    const float* wq = w3 + (q << 5);  // uniform -> s_load
#pragma unroll
    for (int s = 0; s < 2; ++s) {
      const float* es = esp + (size_t)(s0 + s) * HDIM + (q << 5);  // uniform
#pragma unroll
      for (int k = 0; k < 8; ++k) {
        acc[s] = g4(es[4 * k + 0], es[4 * k + 1], es[4 * k + 2], es[4 * k + 3],
                    wq[4 * k + 0], wq[4 * k + 1], wq[4 * k + 2], wq[4 * k + 3],
                    ev[k], acc[s]);
      }
    }
  }
  const float Cv = *Cptr;  // uniform -> s_load
  if (n < N) {
    out[(size_t)(s0 + 0) * N + n] = fmaf(-2.f, acc[0], Cv);
    out[(size_t)(s0 + 1) * N + n] = fmaf(-2.f, acc[1], Cv);
  }
}

extern "C" void kernel_launch(void* const* d_in, const int* in_sizes, int n_in,
                              void* d_out, int out_size, void* d_ws, size_t ws_size,
                              hipStream_t stream) {
  const float* sess = (const float*)d_in[0];
  const float* emb  = (const float*)d_in[1];
  const float* W1   = (const float*)d_in[2];
  const float* b1   = (const float*)d_in[3];
  const float* W2   = (const float*)d_in[4];
  const float* b2   = (const float*)d_in[5];
  const float* W3   = (const float*)d_in[6];
  const float* b3   = (const float*)d_in[7];
  float* out = (float*)d_out;
  const int B = in_sizes[0] / EDIM;   // 64
  const int N = in_sizes[1] / EDIM;   // 20000

  const int tiles = (N + 63) / 64;    // 313
  const int npad = tiles * 64;        // 20032

  float* etpT4 = (float*)d_ws;                        // 128*npad floats
  float* esp   = etpT4 + (size_t)HDIM * npad;         // B*128 floats
  float* Cp    = esp + (size_t)BSES * HDIM;           // 1 float

  const int nbTP = (N + 31) / 32;                     // 625
  const int nbSP = (B * HDIM + 255) / 256;            // 32
  taa_k1<<<nbTP + nbSP, 256, 0, stream>>>(sess, W1, b1, emb, W2, b2, W3, b3,
                                          etpT4, esp, Cp, N, npad, nbTP);
  // tiles*32 waves (32 session-groups of 2 per tile), 4 waves/block.
  taa_k2<<<tiles * 8, 256, 0, stream>>>(etpT4, esp, W3, Cp, out, N, npad);
}